// Round 4
// baseline (29.415 us; speedup 1.0000x reference)
//
#include <hip/hip_runtime.h>

// NeuralPonds: flavor = int(abs(np-pairwise-sum over d_model)) % 10000,
// out[token] = tables[pond[token], flavor]  (row of 1024 f32)
//
// Bit-exact numpy pairwise sum (verified on HW, absmax 0.0): 64 sequential
// chains r[b][j] = sum_k a[b*128 + j + 8k] (numpy accumulation order)
// combined by a balanced binary tree == 64-lane shfl_xor butterfly.
//
// R4: two-kernel phase split (R3, -7.5%) + barrier-free k1. Each wave's
// reduction is self-contained (R2 proved LDS transpose == strided global
// reads), so k1 drops LDS + __syncthreads entirely: pure read stream,
// no lockstep drain. k2 = cached gather + nontemporal write stream.

#define POND_MOD 10000
#define D_MODEL  1024

typedef float f32x4 __attribute__((ext_vector_type(4)));

__global__ __launch_bounds__(256) void np_flavor_kernel(
    const float* __restrict__ ctx,      // [ntok, 1024]
    const int*   __restrict__ pond,     // [ntok]
    int*         __restrict__ idxbuf,   // [ntok] combined pond*10000+flavor
    int ntok)
{
    const int lane  = threadIdx.x & 63;
    const int wid   = threadIdx.x >> 6;
    const int token = blockIdx.x * 4 + wid;       // one wave per token
    if (token >= ntok) return;

    const float* row = ctx + (size_t)token * D_MODEL;
    const int pd = pond[token];

    // lane l = 8b + j owns chain sum_k a[b*128 + j + 8k], k = 0..15,
    // strictly sequential adds (numpy order). 16 independent loads issue
    // back-to-back; L1 absorbs the 4x line re-touch.
    const int b = lane >> 3;
    const int j = lane & 7;
    const float* p = row + b * 128 + j;
    float r = p[0];
    #pragma unroll
    for (int k = 1; k < 16; ++k)
        r += p[8 * k];

    // balanced-binary-tree combine across 64 lanes == numpy pairwise tree
    #pragma unroll
    for (int m = 1; m < 64; m <<= 1)
        r += __shfl_xor(r, m, 64);

    if (lane == 0) {
        const int flavor = ((int)fabsf(r)) % POND_MOD;
        idxbuf[token] = pd * POND_MOD + flavor;
    }
}

__global__ __launch_bounds__(256) void np_gather_kernel(
    const float* __restrict__ tables,   // [10*10000, 1024]
    const int*   __restrict__ idxbuf,   // [ntok]
    float*       __restrict__ out,      // [ntok, 1024]
    int ntok)
{
    const int lane  = threadIdx.x & 63;
    const int wid   = threadIdx.x >> 6;
    const int token = blockIdx.x * 4 + wid;
    if (token >= ntok) return;

    const int idx = __builtin_amdgcn_readfirstlane(idxbuf[token]);
    const f32x4* src = (const f32x4*)(tables + (size_t)idx * D_MODEL);
    f32x4*       dst = (f32x4*)(out + (size_t)token * D_MODEL);

    #pragma unroll
    for (int k = 0; k < 4; ++k) {
        f32x4 v = src[k * 64 + lane];                        // hot rows: L2/L3
        __builtin_nontemporal_store(v, &dst[k * 64 + lane]); // pure stream out
    }
}

// fallback single kernel (ws too small) — R1-verified path
__global__ __launch_bounds__(256) void np_fused_kernel(
    const float* __restrict__ ctx, const int* __restrict__ pond,
    const float* __restrict__ tables, float* __restrict__ out, int ntok)
{
    const int lane  = threadIdx.x & 63;
    const int wid   = threadIdx.x >> 6;
    const int token = blockIdx.x * 4 + wid;
    if (token >= ntok) return;

    const float* row = ctx + (size_t)token * D_MODEL;
    const int b = lane >> 3, j = lane & 7;
    const float* p = row + b * 128 + j;
    float r = p[0];
    #pragma unroll
    for (int k = 1; k < 16; ++k) r += p[8 * k];
    #pragma unroll
    for (int m = 1; m < 64; m <<= 1) r += __shfl_xor(r, m, 64);

    const int flavor = ((int)fabsf(r)) % POND_MOD;
    const int pd = pond[token];
    const float4* src = (const float4*)(tables + ((size_t)pd * POND_MOD + flavor) * D_MODEL);
    float4*       dst = (float4*)(out + (size_t)token * D_MODEL);
    #pragma unroll
    for (int k = 0; k < 4; ++k) dst[k * 64 + lane] = src[k * 64 + lane];
}

extern "C" void kernel_launch(void* const* d_in, const int* in_sizes, int n_in,
                              void* d_out, int out_size, void* d_ws, size_t ws_size,
                              hipStream_t stream) {
    const float* ctx    = (const float*)d_in[0];
    const int*   pond   = (const int*)d_in[1];
    const float* tables = (const float*)d_in[2];
    float*       out    = (float*)d_out;

    const int ntok   = in_sizes[1];               // 16384 tokens
    const int blocks = (ntok + 3) / 4;

    if (ws_size >= (size_t)ntok * sizeof(int)) {
        int* idxbuf = (int*)d_ws;
        np_flavor_kernel<<<blocks, 256, 0, stream>>>(ctx, pond, idxbuf, ntok);
        np_gather_kernel<<<blocks, 256, 0, stream>>>(tables, idxbuf, out, ntok);
    } else {
        np_fused_kernel<<<blocks, 256, 0, stream>>>(ctx, pond, tables, out, ntok);
    }
}

// Round 5
// 28.011 us; speedup vs baseline: 1.0501x; 1.0501x over previous
//
#include <hip/hip_runtime.h>

// NeuralPonds: flavor = int(abs(np-pairwise-sum over d_model)) % 10000,
// out[token] = tables[pond[token], flavor]  (row of 1024 f32)
//
// Bit-exact numpy pairwise sum (verified on HW, absmax 0.0): 64 sequential
// chains r[b][j] = sum_k a[b*128 + j + 8k] (numpy accumulation order)
// combined by a balanced binary tree == 64-lane shfl_xor butterfly.
//
// Ladder: R1 fused strided 30.1 | R2 fused +LDS 30.0 | R3 split (LDS k1) 27.8
// | R4 split strided k1 29.4 (REGRESS: pure-read kernel needs coalesced
// float4; strided scalar loads are the limiter there).
//
// R5: R3 exactly, but k1's __syncthreads() -> wave-local lgkmcnt(0) fence.
// Each wave only touches its own LDS region; DS ops are wave-wide, so
// draining lgkmcnt makes all 64 lanes' writes visible wave-internally.
// No s_barrier => no vmcnt(0) drain coupling, no 4-wave lockstep.

#define POND_MOD 10000
#define D_MODEL  1024
#define PADDED   132            // 128 + 4 pad floats per 128-elem sub-block
#define WAVE_LDS (8 * PADDED)

typedef float f32x4 __attribute__((ext_vector_type(4)));

__global__ __launch_bounds__(256) void np_flavor_kernel(
    const float* __restrict__ ctx,      // [ntok, 1024]
    const int*   __restrict__ pond,     // [ntok]
    int*         __restrict__ idxbuf,   // [ntok] combined pond*10000+flavor
    int ntok)
{
    __shared__ float lds[4 * WAVE_LDS];

    const int lane  = threadIdx.x & 63;
    const int wid   = threadIdx.x >> 6;
    const int token = blockIdx.x * 4 + wid;       // one wave per token
    if (token >= ntok) return;                    // safe: no block barrier

    // coalesced nontemporal load of the 4KB ctx row (streamed, never reused)
    const f32x4* row4 = (const f32x4*)(ctx + (size_t)token * D_MODEL);
    int pd = pond[token];
    f32x4 v[4];
    #pragma unroll
    for (int t = 0; t < 4; ++t)
        v[t] = __builtin_nontemporal_load(&row4[t * 64 + lane]);

    // transpose into this wave's padded LDS region
    // element e = 256t + 4l + s -> addr (2t + (l>>5))*132 + 4*(l&31) + s
    float* w = lds + wid * WAVE_LDS;
    const int l31 = lane & 31;
    const int hb  = lane >> 5;
    #pragma unroll
    for (int t = 0; t < 4; ++t)
        *(f32x4*)(w + (2 * t + hb) * PADDED + 4 * l31) = v[t];

    // wave-local visibility: DS instructions are wave-wide; once lgkmcnt
    // drains, every lane's write is in LDS. No cross-wave region => no
    // s_barrier. sched_barrier pins ordering (rule #18 caution).
    asm volatile("s_waitcnt lgkmcnt(0)" ::: "memory");
    __builtin_amdgcn_sched_barrier(0);

    // numpy-order chain: lane l = 8b + j sums a[b*128 + j + 8k], k=0..15
    const int b = lane >> 3;
    const int j = lane & 7;
    const float* rp = w + b * PADDED + j;
    float r = rp[0];
    #pragma unroll
    for (int k = 1; k < 16; ++k)
        r += rp[8 * k];

    // balanced-binary-tree combine across 64 lanes == numpy pairwise tree
    #pragma unroll
    for (int m = 1; m < 64; m <<= 1)
        r += __shfl_xor(r, m, 64);

    if (lane == 0) {
        const int flavor = ((int)fabsf(r)) % POND_MOD;
        idxbuf[token] = pd * POND_MOD + flavor;
    }
}

__global__ __launch_bounds__(256) void np_gather_kernel(
    const float* __restrict__ tables,   // [10*10000, 1024]
    const int*   __restrict__ idxbuf,   // [ntok]
    float*       __restrict__ out,      // [ntok, 1024]
    int ntok)
{
    const int lane  = threadIdx.x & 63;
    const int wid   = threadIdx.x >> 6;
    const int token = blockIdx.x * 4 + wid;
    if (token >= ntok) return;

    const int idx = __builtin_amdgcn_readfirstlane(idxbuf[token]);
    const f32x4* src = (const f32x4*)(tables + (size_t)idx * D_MODEL);
    f32x4*       dst = (f32x4*)(out + (size_t)token * D_MODEL);

    #pragma unroll
    for (int k = 0; k < 4; ++k) {
        f32x4 v = src[k * 64 + lane];                        // hot rows: L2/L3
        __builtin_nontemporal_store(v, &dst[k * 64 + lane]); // pure stream out
    }
}

// fallback single kernel (ws too small) — R1-verified path
__global__ __launch_bounds__(256) void np_fused_kernel(
    const float* __restrict__ ctx, const int* __restrict__ pond,
    const float* __restrict__ tables, float* __restrict__ out, int ntok)
{
    const int lane  = threadIdx.x & 63;
    const int wid   = threadIdx.x >> 6;
    const int token = blockIdx.x * 4 + wid;
    if (token >= ntok) return;

    const float* row = ctx + (size_t)token * D_MODEL;
    const int b = lane >> 3, j = lane & 7;
    const float* p = row + b * 128 + j;
    float r = p[0];
    #pragma unroll
    for (int k = 1; k < 16; ++k) r += p[8 * k];
    #pragma unroll
    for (int m = 1; m < 64; m <<= 1) r += __shfl_xor(r, m, 64);

    const int flavor = ((int)fabsf(r)) % POND_MOD;
    const int pd = pond[token];
    const float4* src = (const float4*)(tables + ((size_t)pd * POND_MOD + flavor) * D_MODEL);
    float4*       dst = (float4*)(out + (size_t)token * D_MODEL);
    #pragma unroll
    for (int k = 0; k < 4; ++k) dst[k * 64 + lane] = src[k * 64 + lane];
}

extern "C" void kernel_launch(void* const* d_in, const int* in_sizes, int n_in,
                              void* d_out, int out_size, void* d_ws, size_t ws_size,
                              hipStream_t stream) {
    const float* ctx    = (const float*)d_in[0];
    const int*   pond   = (const int*)d_in[1];
    const float* tables = (const float*)d_in[2];
    float*       out    = (float*)d_out;

    const int ntok   = in_sizes[1];               // 16384 tokens
    const int blocks = (ntok + 3) / 4;

    if (ws_size >= (size_t)ntok * sizeof(int)) {
        int* idxbuf = (int*)d_ws;
        np_flavor_kernel<<<blocks, 256, 0, stream>>>(ctx, pond, idxbuf, ntok);
        np_gather_kernel<<<blocks, 256, 0, stream>>>(tables, idxbuf, out, ntok);
    } else {
        np_fused_kernel<<<blocks, 256, 0, stream>>>(ctx, pond, tables, out, ntok);
    }
}